// Round 20
// baseline (132.376 us; speedup 1.0000x reference)
//
#include <hip/hip_runtime.h>
#include <hip/hip_bf16.h>

// Shapes (fixed by the reference)
#define BB 16
#define HH 64
#define WW 64
#define CC 256
#define OH 128
#define OW 128
#define FF 256

typedef __attribute__((ext_vector_type(8))) short bf16x8;
typedef __attribute__((ext_vector_type(4))) float f32x4;

// RNE float -> bf16 bits
__device__ __forceinline__ short f2bf(float x) {
    union { float f; unsigned u; } v; v.f = x;
    unsigned r = v.u + 0x7fffu + ((v.u >> 16) & 1u);
    return (short)(r >> 16);
}

// packed f32x2 -> bf16x2 (1 VALU instr)
__device__ __forceinline__ unsigned cvtpk(float lo, float hi) {
    unsigned r;
    asm("v_cvt_pk_bf16_f32 %0, %1, %2" : "=v"(r) : "v"(lo), "v"(hi));
    return r;
}

__device__ __forceinline__ float bf2f(short s) {
    union { unsigned u; float f; } v;
    v.u = ((unsigned)(unsigned short)s) << 16;
    return v.f;
}

// prep (2080 blocks x 256):
//  blocks 0..2047: X f32 -> Xbf bf16 (8192 elems each), row-major like X
//  blocks 2048..2079: pwtF fragment-linear (r18 layout)
__global__ void prep_kernel(const float* __restrict__ X, const float* __restrict__ pw,
                            short* __restrict__ Xbf, short* __restrict__ pwtF) {
    const int blk = blockIdx.x, tid = threadIdx.x;
    if (blk < 2048) {
        const float4* src = reinterpret_cast<const float4*>(X);
        bf16x8* dst = reinterpret_cast<bf16x8*>(Xbf);
        #pragma unroll
        for (int k = 0; k < 4; ++k) {
            const int v2 = blk * 2048 + k * 512 + tid * 2;   // float4 index
            float4 a = src[v2], c = src[v2 + 1];
            union { unsigned u[4]; bf16x8 v; } pk;
            pk.u[0] = cvtpk(a.x, a.y); pk.u[1] = cvtpk(a.z, a.w);
            pk.u[2] = cvtpk(c.x, c.y); pk.u[3] = cvtpk(c.z, c.w);
            dst[v2 >> 1] = pk.v;
        }
    } else {
        const int e    = (blk - 2048) * 256 + tid;
        const int lane = e & 63;
        const int ni   = (e >> 6) & 3;
        const int kk   = (e >> 8) & 7;
        const int wc   = e >> 11;
        const int f    = wc * 64 + ni * 16 + (lane & 15);
        const int c0   = kk * 32 + (lane >> 4) * 8;
        bf16x8 v;
        #pragma unroll
        for (int j = 0; j < 8; ++j) v[j] = f2bf(pw[(size_t)(c0 + j) * FF + f]);
        reinterpret_cast<bf16x8*>(pwtF)[e] = v;
    }
}

// One block = one (b, oh) output row, 4 quarters of 32 ow.
// Waves 0-3 = producers: wave-private bf16 DMA staging (6 x 1KB global_load_lds
//   per quarter; one DMA covers both input rows of a column: lane<32 -> row0,
//   lane>=32 -> row1). Each wave reads ONLY its own staged window (per-wave
//   vmcnt sound). Depthwise computed 2 ow per pass (lane = 8 channels,
//   grp = lane>>5 = ow parity, lane-constant weights) -> t_lds[q&1].
// Waves 4-7 = consumers: MFMA pointwise (fragment-linear B) + f32x4 stores.
// LDS = 48 KiB xraw + 32 KiB t_lds = 80 KiB -> 2 blocks/CU (16 waves).
__global__ __launch_bounds__(512, 4)
void sepconvt_kernel(const short* __restrict__ Xbf,
                     const float* __restrict__ dw,
                     const short* __restrict__ pwtF,
                     const float* __restrict__ bias,
                     float* __restrict__ out) {
    __shared__ __align__(16) char xraw[49152];     // 2 bufs x 4 waves x 6 cols x [2 rows][256ch bf16]
    __shared__ bf16x8 t_lds[2][32 * 32];           // 2 x 16 KiB

    const int tid  = threadIdx.x;
    const int wid  = tid >> 6;
    const int lane = tid & 63;
    const int blk  = blockIdx.x;          // b*OH + oh
    const int oh = blk & (OH - 1);
    const int b  = blk >> 7;

    // Row taps: even oh -> (r=1, i=oh/2), (r=3, i=oh/2-1); odd -> (r=0,(oh+1)/2),(r=2,(oh-1)/2)
    int r0, r1, i0, i1;
    if (oh & 1) { r0 = 0; i0 = (oh + 1) >> 1; r1 = 2; i1 = (oh - 1) >> 1; }
    else        { r0 = 1; i0 = oh >> 1;       r1 = 3; i1 = (oh >> 1) - 1; }
    const bool va0 = (unsigned)i0 < HH;
    const bool va1 = (unsigned)i1 < HH;

    if (wid < 4) {
        // ---------------- producer persona ----------------
        const int w   = wid;
        const int grp = lane >> 5;        // 0: even-ow lane group / row0 stager
        const int ch  = lane & 31;        // 8-channel slot
        const int c0  = ch << 3;

        const size_t xrow0 = (size_t)(b * HH + (va0 ? i0 : 0)) * WW * CC;
        const size_t xrow1 = (size_t)(b * HH + (va1 ? i1 : 0)) * WW * CC;
        const size_t xrowS = grp ? xrow1 : xrow0;   // this lane stages row grp

        // weights for THIS lane's parity grp: je tap s = grp?0:1, jo tap s = grp?2:3
        float we0[8], wo0[8], we1[8], wo1[8];
        {
            const int se = grp ? 0 : 1;
            const int so = grp ? 2 : 3;
            const float4* d4;
            #pragma unroll
            for (int h = 0; h < 2; ++h) {
                d4 = reinterpret_cast<const float4*>(dw + (r0 * 4 + se) * CC + c0) + h;
                float4 a = *d4;
                we0[h*4+0]=a.x; we0[h*4+1]=a.y; we0[h*4+2]=a.z; we0[h*4+3]=a.w;
                d4 = reinterpret_cast<const float4*>(dw + (r0 * 4 + so) * CC + c0) + h;
                a = *d4;
                wo0[h*4+0]=a.x; wo0[h*4+1]=a.y; wo0[h*4+2]=a.z; wo0[h*4+3]=a.w;
                d4 = reinterpret_cast<const float4*>(dw + (r1 * 4 + se) * CC + c0) + h;
                a = *d4;
                we1[h*4+0]=a.x; we1[h*4+1]=a.y; we1[h*4+2]=a.z; we1[h*4+3]=a.w;
                d4 = reinterpret_cast<const float4*>(dw + (r1 * 4 + so) * CC + c0) + h;
                a = *d4;
                wo1[h*4+0]=a.x; wo1[h*4+1]=a.y; wo1[h*4+2]=a.z; wo1[h*4+3]=a.w;
            }
            if (!va0) {
                #pragma unroll
                for (int e = 0; e < 8; ++e) { we0[e]=0.f; wo0[e]=0.f; }
            }
            if (!va1) {
                #pragma unroll
                for (int e = 0; e < 8; ++e) { we1[e]=0.f; wo1[e]=0.f; }
            }
        }

        // stage quarter q's wave-private window: 6 DMAs, each covers both rows
        auto STAGE = [&](int q, int qb) {
            const int W0  = q * 32 + w * 8;
            const int jlo = (W0 >> 1) - 1;
            const int base = qb * 24576 + w * 6144;
            #pragma unroll
            for (int ci = 0; ci < 6; ++ci) {
                int j = jlo + ci;
                j = j < 0 ? 0 : (j > WW - 1 ? WW - 1 : j);
                __builtin_amdgcn_global_load_lds(
                    (const __attribute__((address_space(1))) unsigned*)(Xbf + xrowS + (size_t)j * CC + c0),
                    (__attribute__((address_space(3))) unsigned*)(xraw + base + ci * 1024),
                    16, 0, 0);
            }
        };

        auto PRODUCE = [&](int q, int qb) {
            const char* xw = xraw + qb * 24576 + w * 6144;
            const int W0 = q * 32 + w * 8;
            const int o0 = w * 8;
            #pragma unroll
            for (int k = 0; k < 4; ++k) {
                // this lane's ow = W0 + 2k + grp; local cols: je = k+1+grp, jo = k+grp
                const int jeL = k + 1 + grp;
                const int joL = k + grp;
                bf16x8 xe0 = *reinterpret_cast<const bf16x8*>(xw + jeL * 1024 + 0   + ch * 16);
                bf16x8 xe1 = *reinterpret_cast<const bf16x8*>(xw + jeL * 1024 + 512 + ch * 16);
                bf16x8 xo0 = *reinterpret_cast<const bf16x8*>(xw + joL * 1024 + 0   + ch * 16);
                bf16x8 xo1 = *reinterpret_cast<const bf16x8*>(xw + joL * 1024 + 512 + ch * 16);
                const bool kill_o = (W0 == 0   && k == 0 && grp == 0);  // jo = -1
                const bool kill_e = (W0 == 120 && k == 3 && grp == 1);  // je = 64
                float a8[8];
                #pragma unroll
                for (int e = 0; e < 8; ++e) {
                    const float fe0 = kill_e ? 0.f : bf2f(xe0[e]);
                    const float fe1 = kill_e ? 0.f : bf2f(xe1[e]);
                    const float fo0 = kill_o ? 0.f : bf2f(xo0[e]);
                    const float fo1 = kill_o ? 0.f : bf2f(xo1[e]);
                    a8[e] = we0[e]*fe0 + wo0[e]*fo0 + we1[e]*fe1 + wo1[e]*fo1;
                }
                union { unsigned u[4]; bf16x8 v; } pk;
                pk.u[0] = cvtpk(a8[0], a8[1]); pk.u[1] = cvtpk(a8[2], a8[3]);
                pk.u[2] = cvtpk(a8[4], a8[5]); pk.u[3] = cvtpk(a8[6], a8[7]);
                const int owl = o0 + 2 * k + grp;
                t_lds[qb][owl * 32 + (ch ^ (owl & 7))] = pk.v;
            }
        };

        STAGE(0, 0);
        #pragma unroll
        for (int q = 0; q < 4; ++q) {
            if (q < 3) {
                STAGE(q + 1, (q + 1) & 1);
                asm volatile("s_waitcnt vmcnt(6)" ::: "memory");   // own S(q) landed; S(q+1) in flight
            } else {
                asm volatile("s_waitcnt vmcnt(0)" ::: "memory");
            }
            __builtin_amdgcn_sched_barrier(0);
            PRODUCE(q, q & 1);
            asm volatile("s_waitcnt lgkmcnt(0)" ::: "memory");     // own t_lds writes drained
            __builtin_amdgcn_sched_barrier(0);
            asm volatile("s_barrier" ::: "memory");                // tile q ready
        }
    } else {
        // ---------------- consumer persona (r18-identical) ----------------
        const int wc  = wid - 4;          // 0..3 -> f block
        const int lr  = lane & 15;
        const int lk8 = lane >> 4;
        const bf16x8* pvF = reinterpret_cast<const bf16x8*>(pwtF) + (size_t)wc * 2048 + lane;

        f32x4 bv[4];
        #pragma unroll
        for (int ni = 0; ni < 4; ++ni)
            bv[ni] = *reinterpret_cast<const f32x4*>(&bias[wc * 64 + ni * 16 + lk8 * 4]);

        #pragma unroll
        for (int q = 0; q < 4; ++q) {
            asm volatile("s_barrier" ::: "memory");    // wait tile q
            __builtin_amdgcn_sched_barrier(0);
            const int qb = q & 1;

            f32x4 acc[2][4];
            #pragma unroll
            for (int mi = 0; mi < 2; ++mi)
                #pragma unroll
                for (int ni = 0; ni < 4; ++ni)
                    acc[mi][ni] = (f32x4){0.f, 0.f, 0.f, 0.f};

            #pragma unroll
            for (int kk = 0; kk < 8; ++kk) {
                const int kg = kk * 4 + lk8;
                bf16x8 af[2], bfr[4];
                #pragma unroll
                for (int mi = 0; mi < 2; ++mi) {
                    const int row = mi * 16 + lr;
                    af[mi] = t_lds[qb][row * 32 + (kg ^ (row & 7))];
                }
                #pragma unroll
                for (int ni = 0; ni < 4; ++ni)
                    bfr[ni] = pvF[(kk * 4 + ni) * 64];   // dense 1KB wave burst
                #pragma unroll
                for (int mi = 0; mi < 2; ++mi)
                    #pragma unroll
                    for (int ni = 0; ni < 4; ++ni)
                        acc[mi][ni] = __builtin_amdgcn_mfma_f32_16x16x32_bf16(
                            bfr[ni], af[mi], acc[mi][ni], 0, 0, 0);
            }

            float* obase = out + ((size_t)(b * OH + oh) * OW + q * 32) * FF;
            #pragma unroll
            for (int ni = 0; ni < 4; ++ni) {
                const int f0 = wc * 64 + ni * 16 + lk8 * 4;
                #pragma unroll
                for (int mi = 0; mi < 2; ++mi) {
                    const int ow = mi * 16 + lr;
                    f32x4 v = acc[mi][ni] + bv[ni];
                    v[0] = v[0] > 0.f ? v[0] : 0.f;
                    v[1] = v[1] > 0.f ? v[1] : 0.f;
                    v[2] = v[2] > 0.f ? v[2] : 0.f;
                    v[3] = v[3] > 0.f ? v[3] : 0.f;
                    *reinterpret_cast<f32x4*>(&obase[(size_t)ow * FF + f0]) = v;
                }
            }
        }
    }
}

extern "C" void kernel_launch(void* const* d_in, const int* in_sizes, int n_in,
                              void* d_out, int out_size, void* d_ws, size_t ws_size,
                              hipStream_t stream) {
    (void)in_sizes; (void)n_in; (void)out_size; (void)ws_size;
    const float* X    = (const float*)d_in[0];
    const float* dw   = (const float*)d_in[1];
    const float* pw   = (const float*)d_in[2];
    const float* bias = (const float*)d_in[3];
    float* out = (float*)d_out;

    short* Xbf  = (short*)d_ws;                      // 33,554,432 B
    short* pwtF = (short*)((char*)d_ws + 33554432);  // 131,072 B

    prep_kernel<<<dim3(2080), dim3(256), 0, stream>>>(X, pw, Xbf, pwtF);
    sepconvt_kernel<<<dim3(BB * OH), dim3(512), 0, stream>>>(Xbf, dw, pwtF, bias, out);
}